// Round 4
// baseline (20835.982 us; speedup 1.0000x reference)
//
#include <hip/hip_runtime.h>
#include <hip/hip_fp16.h>

typedef _Float16 h8 __attribute__((ext_vector_type(8)));
typedef _Float16 h4 __attribute__((ext_vector_type(4)));
typedef float f4 __attribute__((ext_vector_type(4)));

#define DEV __device__ __forceinline__

DEV float sigm(float x) { return 1.f / (1.f + __expf(-x)); }
DEV float tanhfast(float x) {
    x = fminf(fmaxf(x, -15.f), 15.f);
    float e = __expf(2.f * x);
    return (e - 1.f) / (e + 1.f);
}
DEV h8 h8zero() {
    h8 v;
#pragma unroll
    for (int e = 0; e < 8; ++e) v[e] = (_Float16)0.f;
    return v;
}

// ---------------- software grid barrier (sense-reversing, agent scope) ------
// bar[0] = arrival counter, bar[1] = generation
DEV void gbar(unsigned* bar, unsigned nblocks) {
    __syncthreads();
    if (threadIdx.x == 0) {
        __threadfence();  // agent-scope release of this block's prior stores
        unsigned g = __hip_atomic_load(&bar[1], __ATOMIC_RELAXED, __HIP_MEMORY_SCOPE_AGENT);
        unsigned prev = __hip_atomic_fetch_add(&bar[0], 1u, __ATOMIC_ACQ_REL, __HIP_MEMORY_SCOPE_AGENT);
        if (prev + 1u == nblocks) {
            __hip_atomic_store(&bar[0], 0u, __ATOMIC_RELAXED, __HIP_MEMORY_SCOPE_AGENT);
            __hip_atomic_store(&bar[1], g + 1u, __ATOMIC_RELEASE, __HIP_MEMORY_SCOPE_AGENT);
        } else {
            unsigned cur;
            do {
                __builtin_amdgcn_s_sleep(2);
                cur = __hip_atomic_load(&bar[1], __ATOMIC_ACQUIRE, __HIP_MEMORY_SCOPE_AGENT);
            } while (cur == g);
        }
    }
    __syncthreads();
}

__global__ void k_zero_bar(unsigned* bar) { bar[0] = 0u; bar[1] = 0u; }

// ---------------- fp32 -> fp16 cast (embW) ----------------
__global__ void k_cast_f2h(const float* __restrict__ in, _Float16* __restrict__ out, int n4) {
    int i = blockIdx.x * blockDim.x + threadIdx.x;
    if (i < n4) {
        float4 v = reinterpret_cast<const float4*>(in)[i];
        h4 o;
        o[0] = (_Float16)v.x; o[1] = (_Float16)v.y; o[2] = (_Float16)v.z; o[3] = (_Float16)v.w;
        reinterpret_cast<h4*>(out)[i] = o;
    }
}

// ---------------- pack W_ext [4096][1280] ----------------
// row n: g=n>>10 (0=r,1=z,2=hn,3=inn), kk=n&1023
// col k: k<1024 -> h_prev part (W_hh), k>=1024 -> e part (W_ih)
// g=2 (hn): e part zero.  g=3 (inn): h part zero.
__global__ void k_pack_wext(const float* __restrict__ Wih, const float* __restrict__ Whh,
                            _Float16* __restrict__ Wext) {
    int n = blockIdx.x, g = n >> 10, kk = n & 1023;
#pragma unroll
    for (int it = 0; it < 5; ++it) {
        int k = it * 256 + threadIdx.x;
        float v;
        if (k < 1024) v = (g == 3) ? 0.f : Whh[(size_t)(g * 1024 + kk) * 1024 + k];
        else          v = (g == 2) ? 0.f : Wih[(size_t)((g == 3 ? 2048 + kk : g * 1024 + kk)) * 256 + (k - 1024)];
        Wext[(size_t)n * 1280 + k] = (_Float16)v;
    }
}

// ---------------- pack compW_ext [512][1280] = [compW | resW] ----------------
__global__ void k_pack_cwext(const float* __restrict__ compW, const float* __restrict__ resW,
                             _Float16* __restrict__ cWext) {
    int n = blockIdx.x;
#pragma unroll
    for (int it = 0; it < 5; ++it) {
        int k = it * 256 + threadIdx.x;
        float v = (k < 1024) ? compW[(size_t)n * 1024 + k] : resW[(size_t)n * 256 + (k - 1024)];
        cWext[(size_t)n * 1280 + k] = (_Float16)v;
    }
}

// ---------------- e-GEMM: e[M][256] = x[M][256] @ embW[256][256]^T + embb ----
__global__ __launch_bounds__(256, 1) void k_gemm_a32(
    const float* __restrict__ A, const _Float16* __restrict__ W,
    const float* __restrict__ bias, _Float16* __restrict__ C,
    int M, int N, int K, int Ntiles) {
    __shared__ __align__(16) _Float16 sA[128 * 72];
    __shared__ __align__(16) _Float16 sB[128 * 72];
    int tm = blockIdx.x / Ntiles, tn = blockIdx.x % Ntiles;
    int tid = threadIdx.x, lane = tid & 63, w = tid >> 6;
    int wr = w >> 1, wc = w & 1;
    f4 acc[4][4] = {};
    for (int k0 = 0; k0 < K; k0 += 64) {
#pragma unroll
        for (int p = 0; p < 4; ++p) {
            int ch = tid + p * 256;
            int r = ch >> 3, cc = ch & 7;
            const float* ap = A + (size_t)(tm * 128 + r) * K + k0 + cc * 8;
            float4 v0 = *reinterpret_cast<const float4*>(ap);
            float4 v1 = *reinterpret_cast<const float4*>(ap + 4);
            h8 va;
            va[0] = (_Float16)v0.x; va[1] = (_Float16)v0.y; va[2] = (_Float16)v0.z; va[3] = (_Float16)v0.w;
            va[4] = (_Float16)v1.x; va[5] = (_Float16)v1.y; va[6] = (_Float16)v1.z; va[7] = (_Float16)v1.w;
            *reinterpret_cast<h8*>(sA + r * 72 + cc * 8) = va;
            h8 vb = *reinterpret_cast<const h8*>(W + (size_t)(tn * 128 + r) * K + k0 + cc * 8);
            *reinterpret_cast<h8*>(sB + r * 72 + cc * 8) = vb;
        }
        __syncthreads();
#pragma unroll
        for (int kc = 0; kc < 2; ++kc) {
            int ro = lane & 15;
            int ko = kc * 32 + (lane >> 4) * 8;
            h8 af[4], bf[4];
#pragma unroll
            for (int mf = 0; mf < 4; ++mf)
                af[mf] = *reinterpret_cast<const h8*>(sA + (wr * 64 + mf * 16 + ro) * 72 + ko);
#pragma unroll
            for (int nf = 0; nf < 4; ++nf)
                bf[nf] = *reinterpret_cast<const h8*>(sB + (wc * 64 + nf * 16 + ro) * 72 + ko);
#pragma unroll
            for (int mf = 0; mf < 4; ++mf)
#pragma unroll
                for (int nf = 0; nf < 4; ++nf)
                    acc[mf][nf] = __builtin_amdgcn_mfma_f32_16x16x32_f16(af[mf], bf[nf], acc[mf][nf], 0, 0, 0);
        }
        __syncthreads();
    }
#pragma unroll
    for (int nf = 0; nf < 4; ++nf) {
        int col = tn * 128 + wc * 64 + nf * 16 + (lane & 15);
        float bs = bias[col];
#pragma unroll
        for (int mf = 0; mf < 4; ++mf) {
#pragma unroll
            for (int q = 0; q < 4; ++q) {
                int row = tm * 128 + wr * 64 + mf * 16 + (lane >> 4) * 4 + q;
                C[(size_t)row * N + col] = (_Float16)(acc[mf][nf][q] + bs);
            }
        }
    }
}

// ---------------- recurrent kernel (regular launch + software barrier) ------
struct SA { _Float16 A[128 * 72]; _Float16 B[128 * 72]; };
struct SB { _Float16 A[32 * 72]; _Float16 B[512 * 72]; float red[4][32][2]; };
union __align__(16) SM { SA a; SB b; };

#define NBLK 256u

__global__ __launch_bounds__(256, 1) void k_recur(
    const _Float16* __restrict__ e_h,    // [32768][256] token=(b*32+i)*32+j
    const _Float16* __restrict__ Wext,   // [4096][1280]
    const _Float16* __restrict__ cWext,  // [512][1280]
    const float* __restrict__ bih, const float* __restrict__ bhh,    // [3072]
    const float* __restrict__ compb, const float* __restrict__ resb, // [512]
    const float* __restrict__ lng, const float* __restrict__ lnb,    // [512]
    _Float16* __restrict__ hbuf,         // [cell][b][1024]
    float* __restrict__ out,             // [b][i][j][512]  (also h-state storage)
    float* __restrict__ hfinal,          // [b][512]
    unsigned* bar) {
    __shared__ SM sm;
    const int tid = threadIdx.x, lane = tid & 63, w = tid >> 6;
    const int lane15 = lane & 15, hi = lane >> 4;

    for (int d = 0; d < 63; ++d) {
        int i0 = d > 31 ? d - 31 : 0;
        int i1 = d < 31 ? d : 31;
        int ncells = i1 - i0 + 1;
        int Mt = (ncells + 3) >> 2;  // 128-row M tiles (4 cells each)

        // ===== phase A: gates GEMM (K=1280, N=4096) + GRU update -> hbuf =====
        if ((int)blockIdx.x < Mt * 32) {
            int s = blockIdx.x & 31;   // kk slice of 32
            int mt = blockIdx.x >> 5;
            f4 acc[2][8] = {};
            for (int kt = 0; kt < 20; ++kt) {
                int k0 = kt * 64;
                // stage A[128][64]: gather h_prev (fp32 from out) / e (fp16)
#pragma unroll
                for (int p = 0; p < 4; ++p) {
                    int ch = tid + p * 256;
                    int r = ch >> 3, cc = ch & 7;
                    int m = mt * 128 + r;
                    int c = m >> 5; if (c >= ncells) c = ncells - 1;
                    int b = m & 31;
                    int i = i0 + c, j = d - i;
                    int k = k0 + cc * 8;
                    h8 v;
                    if (k < 1024) {
                        const float* src = nullptr;
                        if (k < 512) {
                            if (i > 0) src = out + (((size_t)(((b * 32 + (i - 1)) * 32) + j)) << 9) + k;
                        } else {
                            if (j > 0) src = out + (((size_t)(((b * 32 + i) * 32) + (j - 1))) << 9) + (k - 512);
                        }
                        if (src) {
                            float4 f0 = *reinterpret_cast<const float4*>(src);
                            float4 f1 = *reinterpret_cast<const float4*>(src + 4);
                            v[0] = (_Float16)f0.x; v[1] = (_Float16)f0.y;
                            v[2] = (_Float16)f0.z; v[3] = (_Float16)f0.w;
                            v[4] = (_Float16)f1.x; v[5] = (_Float16)f1.y;
                            v[6] = (_Float16)f1.z; v[7] = (_Float16)f1.w;
                        } else v = h8zero();
                    } else {
                        v = *reinterpret_cast<const h8*>(e_h + ((size_t)((b * 32 + i) * 32 + j) << 8) + (k - 1024));
                    }
                    *reinterpret_cast<h8*>(sm.a.A + r * 72 + cc * 8) = v;
                }
                // stage B[128][64]: rows rr = g*32 + t -> Wext row g*1024 + s*32 + t
#pragma unroll
                for (int p = 0; p < 4; ++p) {
                    int ch = tid + p * 256;
                    int rr = ch >> 3, cc = ch & 7;
                    int g = rr >> 5, t = rr & 31;
                    int n = g * 1024 + s * 32 + t;
                    h8 v = *reinterpret_cast<const h8*>(Wext + (size_t)n * 1280 + k0 + cc * 8);
                    *reinterpret_cast<h8*>(sm.a.B + rr * 72 + cc * 8) = v;
                }
                __syncthreads();
#pragma unroll
                for (int kc = 0; kc < 2; ++kc) {
                    int ko = kc * 32 + hi * 8;
                    h8 af[2], bf[8];
#pragma unroll
                    for (int mf = 0; mf < 2; ++mf)
                        af[mf] = *reinterpret_cast<const h8*>(sm.a.A + (w * 32 + mf * 16 + lane15) * 72 + ko);
#pragma unroll
                    for (int nf = 0; nf < 8; ++nf)
                        bf[nf] = *reinterpret_cast<const h8*>(sm.a.B + ((nf >> 1) * 32 + (nf & 1) * 16 + lane15) * 72 + ko);
#pragma unroll
                    for (int mf = 0; mf < 2; ++mf)
#pragma unroll
                        for (int nf = 0; nf < 8; ++nf)
                            acc[mf][nf] = __builtin_amdgcn_mfma_f32_16x16x32_f16(af[mf], bf[nf], acc[mf][nf], 0, 0, 0);
                }
                __syncthreads();
            }
            // epilogue: fused gates (r,z,hn,inn same lane), write h -> hbuf
#pragma unroll
            for (int mf = 0; mf < 2; ++mf) {
                int rbase = mt * 128 + w * 32 + mf * 16 + hi * 4;
#pragma unroll
                for (int q = 0; q < 4; ++q) {
                    int m = rbase + q;
                    int c = m >> 5;
                    if (c >= ncells) continue;
                    int b = m & 31;
                    int i = i0 + c, j = d - i;
#pragma unroll
                    for (int u = 0; u < 2; ++u) {
                        int kk = s * 32 + u * 16 + lane15;
                        float r_ = sigm(acc[mf][u][q] + bih[kk] + bhh[kk]);
                        float z_ = sigm(acc[mf][2 + u][q] + bih[1024 + kk] + bhh[1024 + kk]);
                        float hn_ = acc[mf][4 + u][q] + bhh[2048 + kk];
                        float in_ = acc[mf][6 + u][q] + bih[2048 + kk];
                        float hp;
                        if (kk < 512)
                            hp = (i == 0) ? 0.f
                                 : out[(((size_t)(((b * 32 + (i - 1)) * 32) + j)) << 9) + kk];
                        else
                            hp = (j == 0) ? 0.f
                                 : out[(((size_t)(((b * 32 + i) * 32) + (j - 1))) << 9) + kk - 512];
                        float n_ = tanhfast(in_ + r_ * hn_);
                        float h_ = (1.f - z_) * n_ + z_ * hp;
                        hbuf[((size_t)(c * 32 + b) << 10) + kk] = (_Float16)h_;
                    }
                }
            }
        }
        gbar(bar, NBLK);

        // ===== phase B: hc = [h|e] @ cWext^T + (compb+resb), LN -> out =====
        if ((int)blockIdx.x < ncells) {
            int c = blockIdx.x, i = i0 + c, j = d - i;
            f4 acc[2][8] = {};
            const _Float16* Ab = hbuf + ((size_t)c << 15);
            for (int kt = 0; kt < 20; ++kt) {
                int k0 = kt * 64;
                {   // stage A[32][64]
                    int r = tid >> 3, cc = tid & 7;
                    int k = k0 + cc * 8;
                    h8 v;
                    if (k < 1024) v = *reinterpret_cast<const h8*>(Ab + ((size_t)r << 10) + k);
                    else v = *reinterpret_cast<const h8*>(e_h + ((size_t)((r * 32 + i) * 32 + j) << 8) + (k - 1024));
                    *reinterpret_cast<h8*>(sm.b.A + r * 72 + cc * 8) = v;
                }
                // stage B[512][64]
#pragma unroll
                for (int p = 0; p < 16; ++p) {
                    int ch = tid + p * 256;
                    int rr = ch >> 3, cc = ch & 7;
                    h8 v = *reinterpret_cast<const h8*>(cWext + (size_t)rr * 1280 + k0 + cc * 8);
                    *reinterpret_cast<h8*>(sm.b.B + rr * 72 + cc * 8) = v;
                }
                __syncthreads();
#pragma unroll
                for (int kc = 0; kc < 2; ++kc) {
                    int ko = kc * 32 + hi * 8;
                    h8 af[2], bf[8];
#pragma unroll
                    for (int mf = 0; mf < 2; ++mf)
                        af[mf] = *reinterpret_cast<const h8*>(sm.b.A + (mf * 16 + lane15) * 72 + ko);
#pragma unroll
                    for (int nf = 0; nf < 8; ++nf)
                        bf[nf] = *reinterpret_cast<const h8*>(sm.b.B + (w * 128 + nf * 16 + lane15) * 72 + ko);
#pragma unroll
                    for (int mf = 0; mf < 2; ++mf)
#pragma unroll
                        for (int nf = 0; nf < 8; ++nf)
                            acc[mf][nf] = __builtin_amdgcn_mfma_f32_16x16x32_f16(af[mf], bf[nf], acc[mf][nf], 0, 0, 0);
                }
                __syncthreads();
            }
            // epilogue: bias + LN over 512 cols
            float s1[2][4], s2[2][4];
#pragma unroll
            for (int mf = 0; mf < 2; ++mf) {
#pragma unroll
                for (int q = 0; q < 4; ++q) {
                    float a1 = 0.f, a2 = 0.f;
#pragma unroll
                    for (int nf = 0; nf < 8; ++nf) {
                        int col = w * 128 + nf * 16 + lane15;
                        float v = acc[mf][nf][q] + compb[col] + resb[col];
                        acc[mf][nf][q] = v;
                        a1 += v; a2 += v * v;
                    }
                    s1[mf][q] = a1; s2[mf][q] = a2;
                }
            }
#pragma unroll
            for (int off = 1; off < 16; off <<= 1) {
#pragma unroll
                for (int mf = 0; mf < 2; ++mf)
#pragma unroll
                    for (int q = 0; q < 4; ++q) {
                        s1[mf][q] += __shfl_xor(s1[mf][q], off, 64);
                        s2[mf][q] += __shfl_xor(s2[mf][q], off, 64);
                    }
            }
            if (lane15 == 0) {
#pragma unroll
                for (int mf = 0; mf < 2; ++mf)
#pragma unroll
                    for (int q = 0; q < 4; ++q) {
                        int b = mf * 16 + hi * 4 + q;
                        sm.b.red[w][b][0] = s1[mf][q];
                        sm.b.red[w][b][1] = s2[mf][q];
                    }
            }
            __syncthreads();
#pragma unroll
            for (int mf = 0; mf < 2; ++mf) {
#pragma unroll
                for (int q = 0; q < 4; ++q) {
                    int b = mf * 16 + hi * 4 + q;
                    float t1 = sm.b.red[0][b][0] + sm.b.red[1][b][0] + sm.b.red[2][b][0] + sm.b.red[3][b][0];
                    float t2 = sm.b.red[0][b][1] + sm.b.red[1][b][1] + sm.b.red[2][b][1] + sm.b.red[3][b][1];
                    float mu = t1 * (1.f / 512.f);
                    float var = t2 * (1.f / 512.f) - mu * mu;
                    float rstd = rsqrtf(var + 1e-5f);
                    size_t ob = ((size_t)((b * 32 + i) * 32 + j)) << 9;
#pragma unroll
                    for (int nf = 0; nf < 8; ++nf) {
                        int col = w * 128 + nf * 16 + lane15;
                        float y = (acc[mf][nf][q] - mu) * rstd * lng[col] + lnb[col];
                        out[ob + col] = y;
                        if (i == 31 && j == 31) hfinal[((size_t)b << 9) + col] = y;
                    }
                }
            }
            __syncthreads();
        }
        gbar(bar, NBLK);
    }
}

extern "C" void kernel_launch(void* const* d_in, const int* in_sizes, int n_in,
                              void* d_out, int out_size, void* d_ws, size_t ws_size,
                              hipStream_t stream) {
    const float* x = (const float*)d_in[0];
    const float* embW = (const float*)d_in[1];
    const float* embb = (const float*)d_in[2];
    const float* Wih = (const float*)d_in[3];
    const float* bih = (const float*)d_in[4];
    const float* Whh = (const float*)d_in[5];
    const float* bhh = (const float*)d_in[6];
    const float* compW = (const float*)d_in[7];
    const float* compb = (const float*)d_in[8];
    const float* resW = (const float*)d_in[9];
    const float* resb = (const float*)d_in[10];
    const float* lng = (const float*)d_in[11];
    const float* lnb = (const float*)d_in[12];
    float* out = (float*)d_out;
    float* hfinal = out + (size_t)32768 * 512;
    (void)in_sizes; (void)n_in; (void)out_size; (void)ws_size;

    // workspace: ~30.8 MB total
    _Float16* p = (_Float16*)d_ws;
    _Float16* e_h = p;    p += 8388608;    // [32768][256]
    _Float16* embW_h = p; p += 65536;      // [256][256]
    _Float16* Wext = p;   p += 5242880;    // [4096][1280]
    _Float16* cWext = p;  p += 655360;     // [512][1280]
    _Float16* hbuf = p;   p += 1048576;    // [32][32][1024]
    unsigned* bar = (unsigned*)p;          // [2]

    k_zero_bar<<<1, 1, 0, stream>>>(bar);
    k_cast_f2h<<<64, 256, 0, stream>>>(embW, embW_h, 16384);
    k_pack_wext<<<4096, 256, 0, stream>>>(Wih, Whh, Wext);
    k_pack_cwext<<<512, 256, 0, stream>>>(compW, resW, cWext);
    // e = x @ embW^T + embb : M=32768, N=256, K=256
    k_gemm_a32<<<512, 256, 0, stream>>>(x, embW_h, embb, e_h, 32768, 256, 256, 2);

    k_recur<<<dim3(NBLK), dim3(256), 0, stream>>>(
        e_h, Wext, cWext, bih, bhh, compb, resb, lng, lnb,
        hbuf, out, hfinal, bar);
}

// Round 6
// 6907.451 us; speedup vs baseline: 3.0165x; 3.0165x over previous
//
#include <hip/hip_runtime.h>
#include <hip/hip_fp16.h>

typedef _Float16 h8 __attribute__((ext_vector_type(8)));
typedef _Float16 h4 __attribute__((ext_vector_type(4)));
typedef float f4 __attribute__((ext_vector_type(4)));

#define DEV __device__ __forceinline__

constexpr unsigned kNumBlk = 256u;

DEV float sigm(float x) { return 1.f / (1.f + __expf(-x)); }
DEV float tanhfast(float x) {
    x = fminf(fmaxf(x, -15.f), 15.f);
    float e = __expf(2.f * x);
    return (e - 1.f) / (e + 1.f);
}
DEV h8 h8zero() {
    h8 v;
#pragma unroll
    for (int e = 0; e < 8; ++e) v[e] = (_Float16)0.f;
    return v;
}

// ---------------- software grid barrier ----------------
// bar[0]=arrival counter, bar[1]=generation.
// KEY: spin with RELAXED loads (plain loads, no cache inv);
// exactly ONE acquire per block per barrier, after exit.
DEV void gbar(unsigned* bar, unsigned nblocks) {
    __syncthreads();
    if (threadIdx.x == 0) {
        __threadfence();  // release: drain stores + L2 writeback
        unsigned g = __hip_atomic_load(&bar[1], __ATOMIC_RELAXED, __HIP_MEMORY_SCOPE_AGENT);
        unsigned prev = __hip_atomic_fetch_add(&bar[0], 1u, __ATOMIC_RELAXED, __HIP_MEMORY_SCOPE_AGENT);
        if (prev + 1u == nblocks) {
            __hip_atomic_store(&bar[0], 0u, __ATOMIC_RELAXED, __HIP_MEMORY_SCOPE_AGENT);
            __hip_atomic_store(&bar[1], g + 1u, __ATOMIC_RELEASE, __HIP_MEMORY_SCOPE_AGENT);
        } else {
            unsigned cur;
            do {
                __builtin_amdgcn_s_sleep(2);
                cur = __hip_atomic_load(&bar[1], __ATOMIC_RELAXED, __HIP_MEMORY_SCOPE_AGENT);
            } while (cur == g);
        }
        (void)__hip_atomic_load(&bar[1], __ATOMIC_ACQUIRE, __HIP_MEMORY_SCOPE_AGENT);
    }
    __syncthreads();
}

// zero bar + ctr + gred (all u32-sized)
__global__ void k_zero(unsigned* ptr, int n) {
    int i = blockIdx.x * 256 + threadIdx.x;
    if (i < n) ptr[i] = 0u;
}

// ---------------- fp32 -> fp16 cast (embW) ----------------
__global__ void k_cast_f2h(const float* __restrict__ in, _Float16* __restrict__ out, int n4) {
    int i = blockIdx.x * blockDim.x + threadIdx.x;
    if (i < n4) {
        float4 v = reinterpret_cast<const float4*>(in)[i];
        h4 o;
        o[0] = (_Float16)v.x; o[1] = (_Float16)v.y; o[2] = (_Float16)v.z; o[3] = (_Float16)v.w;
        reinterpret_cast<h4*>(out)[i] = o;
    }
}

// ---------------- pack W_ext [4096][1280] ----------------
__global__ void k_pack_wext(const float* __restrict__ Wih, const float* __restrict__ Whh,
                            _Float16* __restrict__ Wext) {
    int n = blockIdx.x, g = n >> 10, kk = n & 1023;
#pragma unroll
    for (int it = 0; it < 5; ++it) {
        int k = it * 256 + threadIdx.x;
        float v;
        if (k < 1024) v = (g == 3) ? 0.f : Whh[(size_t)(g * 1024 + kk) * 1024 + k];
        else          v = (g == 2) ? 0.f : Wih[(size_t)((g == 3 ? 2048 + kk : g * 1024 + kk)) * 256 + (k - 1024)];
        Wext[(size_t)n * 1280 + k] = (_Float16)v;
    }
}

// ---------------- pack compW_ext [512][1280] = [compW | resW] ----------------
__global__ void k_pack_cwext(const float* __restrict__ compW, const float* __restrict__ resW,
                             _Float16* __restrict__ cWext) {
    int n = blockIdx.x;
#pragma unroll
    for (int it = 0; it < 5; ++it) {
        int k = it * 256 + threadIdx.x;
        float v = (k < 1024) ? compW[(size_t)n * 1024 + k] : resW[(size_t)n * 256 + (k - 1024)];
        cWext[(size_t)n * 1280 + k] = (_Float16)v;
    }
}

// ---------------- e-GEMM: e[M][256] = x[M][256] @ embW[256][256]^T + embb ----
__global__ __launch_bounds__(256, 1) void k_gemm_a32(
    const float* __restrict__ A, const _Float16* __restrict__ W,
    const float* __restrict__ bias, _Float16* __restrict__ C,
    int M, int N, int K, int Ntiles) {
    __shared__ __align__(16) _Float16 sA[128 * 72];
    __shared__ __align__(16) _Float16 sB[128 * 72];
    int tm = blockIdx.x / Ntiles, tn = blockIdx.x % Ntiles;
    int tid = threadIdx.x, lane = tid & 63, w = tid >> 6;
    int wr = w >> 1, wc = w & 1;
    f4 acc[4][4] = {};
    for (int k0 = 0; k0 < K; k0 += 64) {
#pragma unroll
        for (int p = 0; p < 4; ++p) {
            int ch = tid + p * 256;
            int r = ch >> 3, cc = ch & 7;
            const float* ap = A + (size_t)(tm * 128 + r) * K + k0 + cc * 8;
            float4 v0 = *reinterpret_cast<const float4*>(ap);
            float4 v1 = *reinterpret_cast<const float4*>(ap + 4);
            h8 va;
            va[0] = (_Float16)v0.x; va[1] = (_Float16)v0.y; va[2] = (_Float16)v0.z; va[3] = (_Float16)v0.w;
            va[4] = (_Float16)v1.x; va[5] = (_Float16)v1.y; va[6] = (_Float16)v1.z; va[7] = (_Float16)v1.w;
            *reinterpret_cast<h8*>(sA + r * 72 + cc * 8) = va;
            h8 vb = *reinterpret_cast<const h8*>(W + (size_t)(tn * 128 + r) * K + k0 + cc * 8);
            *reinterpret_cast<h8*>(sB + r * 72 + cc * 8) = vb;
        }
        __syncthreads();
#pragma unroll
        for (int kc = 0; kc < 2; ++kc) {
            int ro = lane & 15;
            int ko = kc * 32 + (lane >> 4) * 8;
            h8 af[4], bf[4];
#pragma unroll
            for (int mf = 0; mf < 4; ++mf)
                af[mf] = *reinterpret_cast<const h8*>(sA + (wr * 64 + mf * 16 + ro) * 72 + ko);
#pragma unroll
            for (int nf = 0; nf < 4; ++nf)
                bf[nf] = *reinterpret_cast<const h8*>(sB + (wc * 64 + nf * 16 + ro) * 72 + ko);
#pragma unroll
            for (int mf = 0; mf < 4; ++mf)
#pragma unroll
                for (int nf = 0; nf < 4; ++nf)
                    acc[mf][nf] = __builtin_amdgcn_mfma_f32_16x16x32_f16(af[mf], bf[nf], acc[mf][nf], 0, 0, 0);
        }
        __syncthreads();
    }
#pragma unroll
    for (int nf = 0; nf < 4; ++nf) {
        int col = tn * 128 + wc * 64 + nf * 16 + (lane & 15);
        float bs = bias[col];
#pragma unroll
        for (int mf = 0; mf < 4; ++mf) {
#pragma unroll
            for (int q = 0; q < 4; ++q) {
                int row = tm * 128 + wr * 64 + mf * 16 + (lane >> 4) * 4 + q;
                C[(size_t)row * N + col] = (_Float16)(acc[mf][nf][q] + bs);
            }
        }
    }
}

// ---------------- recurrent kernel ----------------
struct SA { _Float16 A[128 * 72]; _Float16 B[128 * 72]; };
struct SB { _Float16 A[32 * 72]; _Float16 B[64 * 72]; float red[4][32][2]; };
union __align__(16) SM { SA a; SB b; };

__global__ __launch_bounds__(256, 1) void k_recur(
    const _Float16* __restrict__ e_h,    // [32768][256] token=(b*32+i)*32+j
    const _Float16* __restrict__ Wext,   // [4096][1280]
    const _Float16* __restrict__ cWext,  // [512][1280]
    const float* __restrict__ bih, const float* __restrict__ bhh,    // [3072]
    const float* __restrict__ compb, const float* __restrict__ resb, // [512]
    const float* __restrict__ lng, const float* __restrict__ lnb,    // [512]
    _Float16* __restrict__ hbuf,         // [cell][b][1024]
    float* __restrict__ out,             // [b][i][j][512]  (also h-state)
    float* __restrict__ hfinal,          // [b][512]
    unsigned* bar,                       // [2]
    unsigned* ctr,                       // [63][32] per-(diag,cell) LN counter
    float* gred) {                       // [63][32][32][2] per-(diag,cell,b) sums
    __shared__ SM sm;
    const int tid = threadIdx.x, lane = tid & 63, w = tid >> 6;
    const int lane15 = lane & 15, hi = lane >> 4;

    for (int d = 0; d < 63; ++d) {
        int i0 = d > 31 ? d - 31 : 0;
        int i1 = d < 31 ? d : 31;
        int ncells = i1 - i0 + 1;
        int Mt = (ncells + 3) >> 2;  // 128-row M tiles (4 cells each)

        // ===== phase A: gates GEMM (K=1280, N=4096) + GRU update -> hbuf =====
        if ((int)blockIdx.x < Mt * 32) {
            int s = blockIdx.x & 31;   // kk slice of 32
            int mt = blockIdx.x >> 5;
            f4 acc[2][8] = {};
            for (int kt = 0; kt < 20; ++kt) {
                int k0 = kt * 64;
                // stage A[128][64]: gather h_prev (fp32 from out) / e (fp16)
#pragma unroll
                for (int p = 0; p < 4; ++p) {
                    int ch = tid + p * 256;
                    int r = ch >> 3, cc = ch & 7;
                    int m = mt * 128 + r;
                    int c = m >> 5; if (c >= ncells) c = ncells - 1;
                    int b = m & 31;
                    int i = i0 + c, j = d - i;
                    int k = k0 + cc * 8;
                    h8 v;
                    if (k < 1024) {
                        const float* src = nullptr;
                        if (k < 512) {
                            if (i > 0) src = out + (((size_t)(((b * 32 + (i - 1)) * 32) + j)) << 9) + k;
                        } else {
                            if (j > 0) src = out + (((size_t)(((b * 32 + i) * 32) + (j - 1))) << 9) + (k - 512);
                        }
                        if (src) {
                            float4 f0 = *reinterpret_cast<const float4*>(src);
                            float4 f1 = *reinterpret_cast<const float4*>(src + 4);
                            v[0] = (_Float16)f0.x; v[1] = (_Float16)f0.y;
                            v[2] = (_Float16)f0.z; v[3] = (_Float16)f0.w;
                            v[4] = (_Float16)f1.x; v[5] = (_Float16)f1.y;
                            v[6] = (_Float16)f1.z; v[7] = (_Float16)f1.w;
                        } else v = h8zero();
                    } else {
                        v = *reinterpret_cast<const h8*>(e_h + ((size_t)((b * 32 + i) * 32 + j) << 8) + (k - 1024));
                    }
                    *reinterpret_cast<h8*>(sm.a.A + r * 72 + cc * 8) = v;
                }
                // stage B[128][64]: rows rr = g*32 + t -> Wext row g*1024 + s*32 + t
#pragma unroll
                for (int p = 0; p < 4; ++p) {
                    int ch = tid + p * 256;
                    int rr = ch >> 3, cc = ch & 7;
                    int g = rr >> 5, t = rr & 31;
                    int n = g * 1024 + s * 32 + t;
                    h8 v = *reinterpret_cast<const h8*>(Wext + (size_t)n * 1280 + k0 + cc * 8);
                    *reinterpret_cast<h8*>(sm.a.B + rr * 72 + cc * 8) = v;
                }
                __syncthreads();
#pragma unroll
                for (int kc = 0; kc < 2; ++kc) {
                    int ko = kc * 32 + hi * 8;
                    h8 af[2], bf[8];
#pragma unroll
                    for (int mf = 0; mf < 2; ++mf)
                        af[mf] = *reinterpret_cast<const h8*>(sm.a.A + (w * 32 + mf * 16 + lane15) * 72 + ko);
#pragma unroll
                    for (int nf = 0; nf < 8; ++nf)
                        bf[nf] = *reinterpret_cast<const h8*>(sm.a.B + ((nf >> 1) * 32 + (nf & 1) * 16 + lane15) * 72 + ko);
#pragma unroll
                    for (int mf = 0; mf < 2; ++mf)
#pragma unroll
                        for (int nf = 0; nf < 8; ++nf)
                            acc[mf][nf] = __builtin_amdgcn_mfma_f32_16x16x32_f16(af[mf], bf[nf], acc[mf][nf], 0, 0, 0);
                }
                __syncthreads();
            }
            // epilogue: fused gates (r,z,hn,inn same lane), write h -> hbuf
#pragma unroll
            for (int mf = 0; mf < 2; ++mf) {
                int rbase = mt * 128 + w * 32 + mf * 16 + hi * 4;
#pragma unroll
                for (int q = 0; q < 4; ++q) {
                    int m = rbase + q;
                    int c = m >> 5;
                    if (c >= ncells) continue;
                    int b = m & 31;
                    int i = i0 + c, j = d - i;
#pragma unroll
                    for (int u = 0; u < 2; ++u) {
                        int kk = s * 32 + u * 16 + lane15;
                        float r_ = sigm(acc[mf][u][q] + bih[kk] + bhh[kk]);
                        float z_ = sigm(acc[mf][2 + u][q] + bih[1024 + kk] + bhh[1024 + kk]);
                        float hn_ = acc[mf][4 + u][q] + bhh[2048 + kk];
                        float in_ = acc[mf][6 + u][q] + bih[2048 + kk];
                        float hp;
                        if (kk < 512)
                            hp = (i == 0) ? 0.f
                                 : out[(((size_t)(((b * 32 + (i - 1)) * 32) + j)) << 9) + kk];
                        else
                            hp = (j == 0) ? 0.f
                                 : out[(((size_t)(((b * 32 + i) * 32) + (j - 1))) << 9) + kk - 512];
                        float n_ = tanhfast(in_ + r_ * hn_);
                        float h_ = (1.f - z_) * n_ + z_ * hp;
                        hbuf[((size_t)(c * 32 + b) << 10) + kk] = (_Float16)h_;
                    }
                }
            }
        }
        gbar(bar, kNumBlk);

        // ===== phase B: hc = [h|e] @ cWext^T, 8 col-slices/cell, LN via atomics =====
        if ((int)blockIdx.x < ncells * 8) {
            int c = blockIdx.x >> 3, sl = blockIdx.x & 7;
            int i = i0 + c, j = d - i;
            f4 acc[2] = {};
            const _Float16* Ab = hbuf + ((size_t)c << 15);
            for (int kt = 0; kt < 20; ++kt) {
                int k0 = kt * 64;
                {   // stage A[32][64]
                    int r = tid >> 3, cc = tid & 7;
                    int k = k0 + cc * 8;
                    h8 v;
                    if (k < 1024) v = *reinterpret_cast<const h8*>(Ab + ((size_t)r << 10) + k);
                    else v = *reinterpret_cast<const h8*>(e_h + ((size_t)((r * 32 + i) * 32 + j) << 8) + (k - 1024));
                    *reinterpret_cast<h8*>(sm.b.A + r * 72 + cc * 8) = v;
                }
                // stage W[64][64]: rows sl*64 + rr
#pragma unroll
                for (int p = 0; p < 2; ++p) {
                    int ch = tid + p * 256;
                    int rr = ch >> 3, cc = ch & 7;
                    h8 v = *reinterpret_cast<const h8*>(cWext + (size_t)(sl * 64 + rr) * 1280 + k0 + cc * 8);
                    *reinterpret_cast<h8*>(sm.b.B + rr * 72 + cc * 8) = v;
                }
                __syncthreads();
#pragma unroll
                for (int kc = 0; kc < 2; ++kc) {
                    int ko = kc * 32 + hi * 8;
                    h8 bf = *reinterpret_cast<const h8*>(sm.b.B + (w * 16 + lane15) * 72 + ko);
#pragma unroll
                    for (int mf = 0; mf < 2; ++mf) {
                        h8 af = *reinterpret_cast<const h8*>(sm.b.A + (mf * 16 + lane15) * 72 + ko);
                        acc[mf] = __builtin_amdgcn_mfma_f32_16x16x32_f16(af, bf, acc[mf], 0, 0, 0);
                    }
                }
                __syncthreads();
            }
            // epilogue: bias, block-partial LN sums
            int col = sl * 64 + w * 16 + lane15;
            float cb = compb[col] + resb[col];
            float s1[2][4], s2[2][4];
#pragma unroll
            for (int mf = 0; mf < 2; ++mf)
#pragma unroll
                for (int q = 0; q < 4; ++q) {
                    float v = acc[mf][q] + cb;
                    acc[mf][q] = v;
                    s1[mf][q] = v; s2[mf][q] = v * v;
                }
#pragma unroll
            for (int off = 1; off < 16; off <<= 1)
#pragma unroll
                for (int mf = 0; mf < 2; ++mf)
#pragma unroll
                    for (int q = 0; q < 4; ++q) {
                        s1[mf][q] += __shfl_xor(s1[mf][q], off, 64);
                        s2[mf][q] += __shfl_xor(s2[mf][q], off, 64);
                    }
            if (lane15 == 0)
#pragma unroll
                for (int mf = 0; mf < 2; ++mf)
#pragma unroll
                    for (int q = 0; q < 4; ++q) {
                        int b = mf * 16 + hi * 4 + q;
                        sm.b.red[w][b][0] = s1[mf][q];
                        sm.b.red[w][b][1] = s2[mf][q];
                    }
            __syncthreads();
            // wave 0: one atomicAdd pair per b, then RELEASE-count this slice
            size_t gbase = (((size_t)d * 32 + c) << 6);  // *32*2
            if (tid < 32) {
                int b = tid;
                float t1 = sm.b.red[0][b][0] + sm.b.red[1][b][0] + sm.b.red[2][b][0] + sm.b.red[3][b][0];
                float t2 = sm.b.red[0][b][1] + sm.b.red[1][b][1] + sm.b.red[2][b][1] + sm.b.red[3][b][1];
                atomicAdd(&gred[gbase + b * 2 + 0], t1);
                atomicAdd(&gred[gbase + b * 2 + 1], t2);
            }
            if (tid == 0) {
                __hip_atomic_fetch_add(&ctr[d * 32 + c], 1u, __ATOMIC_RELEASE, __HIP_MEMORY_SCOPE_AGENT);
                unsigned cur;
                do {
                    __builtin_amdgcn_s_sleep(2);
                    cur = __hip_atomic_load(&ctr[d * 32 + c], __ATOMIC_RELAXED, __HIP_MEMORY_SCOPE_AGENT);
                } while (cur < 8u);
                (void)__hip_atomic_load(&ctr[d * 32 + c], __ATOMIC_ACQUIRE, __HIP_MEMORY_SCOPE_AGENT);
            }
            __syncthreads();
            // normalize in-register slice, write out
            float lg = lng[col], lb = lnb[col];
#pragma unroll
            for (int mf = 0; mf < 2; ++mf)
#pragma unroll
                for (int q = 0; q < 4; ++q) {
                    int b = mf * 16 + hi * 4 + q;
                    float t1 = gred[gbase + b * 2 + 0];
                    float t2 = gred[gbase + b * 2 + 1];
                    float mu = t1 * (1.f / 512.f);
                    float var = t2 * (1.f / 512.f) - mu * mu;
                    float rstd = rsqrtf(var + 1e-5f);
                    float y = (acc[mf][q] - mu) * rstd * lg + lb;
                    size_t ob = ((size_t)((b * 32 + i) * 32 + j)) << 9;
                    out[ob + col] = y;
                    if (i == 31 && j == 31) hfinal[((size_t)b << 9) + col] = y;
                }
            __syncthreads();
        }
        gbar(bar, kNumBlk);
    }
}

extern "C" void kernel_launch(void* const* d_in, const int* in_sizes, int n_in,
                              void* d_out, int out_size, void* d_ws, size_t ws_size,
                              hipStream_t stream) {
    const float* x = (const float*)d_in[0];
    const float* embW = (const float*)d_in[1];
    const float* embb = (const float*)d_in[2];
    const float* Wih = (const float*)d_in[3];
    const float* bih = (const float*)d_in[4];
    const float* Whh = (const float*)d_in[5];
    const float* bhh = (const float*)d_in[6];
    const float* compW = (const float*)d_in[7];
    const float* compb = (const float*)d_in[8];
    const float* resW = (const float*)d_in[9];
    const float* resb = (const float*)d_in[10];
    const float* lng = (const float*)d_in[11];
    const float* lnb = (const float*)d_in[12];
    float* out = (float*)d_out;
    float* hfinal = out + (size_t)32768 * 512;
    (void)in_sizes; (void)n_in; (void)out_size; (void)ws_size;

    // workspace: ~31.3 MB
    _Float16* p = (_Float16*)d_ws;
    _Float16* e_h = p;    p += 8388608;    // [32768][256]
    _Float16* embW_h = p; p += 65536;      // [256][256]
    _Float16* Wext = p;   p += 5242880;    // [4096][1280]
    _Float16* cWext = p;  p += 655360;     // [512][1280]
    _Float16* hbuf = p;   p += 1048576;    // [32][32][1024]
    unsigned* bar = (unsigned*)p;          // [2]
    unsigned* ctr = bar + 2;               // [63*32]
    float* gred = (float*)(ctr + 63 * 32); // [63*32*32*2]
    const int kZeroWords = 2 + 63 * 32 + 63 * 32 * 32 * 2;

    k_zero<<<(kZeroWords + 255) / 256, 256, 0, stream>>>(bar, kZeroWords);
    k_cast_f2h<<<64, 256, 0, stream>>>(embW, embW_h, 16384);
    k_pack_wext<<<4096, 256, 0, stream>>>(Wih, Whh, Wext);
    k_pack_cwext<<<512, 256, 0, stream>>>(compW, resW, cWext);
    // e = x @ embW^T + embb : M=32768, N=256, K=256
    k_gemm_a32<<<512, 256, 0, stream>>>(x, embW_h, embb, e_h, 32768, 256, 256, 2);

    k_recur<<<dim3(kNumBlk), dim3(256), 0, stream>>>(
        e_h, Wext, cWext, bih, bhh, compb, resb, lng, lnb,
        hbuf, out, hfinal, bar, ctr, gred);
}